// Round 5
// baseline (455.347 us; speedup 1.0000x reference)
//
#include <hip/hip_runtime.h>

#define LLEN 16384
#define PAD 258  // 516B row stride = 129 dwords; 129%32==1 -> 2-way (free) LDS aliasing

typedef short bf16x8 __attribute__((ext_vector_type(8)));
typedef float f32x4 __attribute__((ext_vector_type(4)));

__device__ __forceinline__ unsigned bfbits(float f) {
  union { float f; unsigned u; } v; v.f = f;
  return (v.u + 0x7FFFu + ((v.u >> 16) & 1u)) >> 16;
}
__device__ __forceinline__ short f2bf(float f) { return (short)bfbits(f); }
__device__ __forceinline__ float bf2f(short s) {
  union { unsigned u; float f; } v;
  v.u = ((unsigned)(unsigned short)s) << 16;
  return v.f;
}
__device__ __forceinline__ float geluf(float x) {  // exact (gf path only)
  return 0.5f * x * (1.0f + erff(x * 0.70710678118654752f));
}
// Fast GELU for the conv chain: activations are ~0.01-0.1 scale there, where
// x*sigmoid(1.702x) differs from exact erf-GELU by <1e-4 abs ->
// ~1e-10 on mask, far below the bf16 path's existing 5e-7.
__device__ __forceinline__ float gelu_fast(float x) {
  return x / (1.0f + __expf(-1.702f * x));
}
__device__ __forceinline__ float waveRedSum(float v) {
  #pragma unroll
  for (int o = 32; o > 0; o >>= 1) v += __shfl_xor(v, o, 64);
  return v;
}

// ---------------- K0: weights -> bf16, zero rowsum ----------------
__global__ __launch_bounds__(256) void k0_convert(
    const float* __restrict__ qw, const float* __restrict__ vw,
    const float* __restrict__ gw, const float* __restrict__ mw,
    short* __restrict__ qwb, short* __restrict__ vwb,
    short* __restrict__ gwb, short* __restrict__ mwb,
    float* __restrict__ rowsum) {
  int idx = blockIdx.x * 256 + threadIdx.x;  // 65536 threads
  qwb[idx] = f2bf(qw[idx]);
  vwb[idx] = f2bf(vw[idx]);
  mwb[idx] = f2bf(mw[idx]);
  if (idx < 4096) {
    int r = idx >> 8, c = idx & 255;
    gwb[idx] = (r < 4) ? f2bf(gw[r * 256 + c]) : (short)0;
  }
  if (idx < 2048) rowsum[idx] = 0.f;
}

// 64e x 32l per-wave GEMM over K=256 from a 32-l slice of the LDS tile.
// A = x fragment (M=l), B = weight fragment (N=e).
// acc[ef][lf][i] <-> e = ef*16 + (lane&15), l = lf*16 + 4*(lane>>4) + i
__device__ __forceinline__ void gemm64x32(const short* __restrict__ wmat,
                                          const short (*xsl)[PAD], int lane,
                                          f32x4 acc[4][2]) {
  int r = lane & 15, h = lane >> 4;
  #pragma unroll
  for (int k0 = 0; k0 < 256; k0 += 32) {
    bf16x8 xfr0 = *(const bf16x8*)&xsl[r][k0 + 8 * h];
    bf16x8 xfr1 = *(const bf16x8*)&xsl[16 + r][k0 + 8 * h];
    #pragma unroll
    for (int ef = 0; ef < 4; ++ef) {
      bf16x8 wfr = *(const bf16x8*)(wmat + (ef * 16 + r) * 256 + k0 + 8 * h);
      acc[ef][0] = __builtin_amdgcn_mfma_f32_16x16x32_bf16(xfr0, wfr, acc[ef][0], 0, 0, 0);
      acc[ef][1] = __builtin_amdgcn_mfma_f32_16x16x32_bf16(xfr1, wfr, acc[ef][1], 0, 0, 0);
    }
  }
}

// Packed epilogue: 4 consecutive-l f32 + bias -> 2 dwords of bf16 (8B store)
__device__ __forceinline__ void store_bf4(short* p, f32x4 a, float bias) {
  uint2 pk;
  pk.x = bfbits(a[0] + bias) | (bfbits(a[1] + bias) << 16);
  pk.y = bfbits(a[2] + bias) | (bfbits(a[3] + bias) << 16);
  *(uint2*)p = pk;
}

// ---------------- K1: focus0 = v_w@x+v_b (bf16), qz = q_w@x+q_b (bf16),
//                      gates = g_w@x+g_b.  512 thr, 8 waves of 64e x 32l ----
__global__ __launch_bounds__(512) void k1_qvg(
    const float* __restrict__ x, const short* __restrict__ vwb,
    const short* __restrict__ qwb, const short* __restrict__ gwb,
    const float* __restrict__ v_b, const float* __restrict__ q_b,
    const float* __restrict__ g_b, short* __restrict__ focus0,
    short* __restrict__ qzS, float* __restrict__ gates) {
  int b = blockIdx.x >> 8, lt = blockIdx.x & 255;
  int l0 = lt << 6;
  __shared__ short xs[64][PAD];
  int t = threadIdx.x;
  {
    int l4 = (t & 15) * 4, cg = t >> 4;  // 16 l-quads x 32 c-pair groups
    const float* xb = x + ((size_t)b << 22) + l0 + l4;
    #pragma unroll
    for (int rep = 0; rep < 4; ++rep) {
      int c = rep * 64 + cg * 2;
      float4 va = *(const float4*)&xb[(size_t)c << 14];
      float4 vb = *(const float4*)&xb[((size_t)c + 1) << 14];
      *(unsigned*)&xs[l4 + 0][c] = bfbits(va.x) | (bfbits(vb.x) << 16);
      *(unsigned*)&xs[l4 + 1][c] = bfbits(va.y) | (bfbits(vb.y) << 16);
      *(unsigned*)&xs[l4 + 2][c] = bfbits(va.z) | (bfbits(vb.z) << 16);
      *(unsigned*)&xs[l4 + 3][c] = bfbits(va.w) | (bfbits(vb.w) << 16);
    }
  }
  __syncthreads();
  int lane = t & 63, wave = t >> 6;
  int we = wave & 3, wl = wave >> 2;  // 4 e-groups x 2 l-halves
  int r = lane & 15, h = lane >> 4;
  int e0 = we << 6;
  const short (*xsl)[PAD] = (const short (*)[PAD])&xs[wl << 5];
  int lbase = l0 + (wl << 5) + 4 * h;
  f32x4 acc[4][2];

  // ---- V GEMM -> focus0 (bf16)
  #pragma unroll
  for (int ef = 0; ef < 4; ++ef)
    #pragma unroll
    for (int lf = 0; lf < 2; ++lf)
      acc[ef][lf] = (f32x4){0.f, 0.f, 0.f, 0.f};
  gemm64x32(vwb + e0 * 256, xsl, lane, acc);
  #pragma unroll
  for (int ef = 0; ef < 4; ++ef) {
    int e = e0 + ef * 16 + r;
    float bias = v_b[e];
    short* rowp = focus0 + ((size_t)((b << 8) | e) << 14) + lbase;
    #pragma unroll
    for (int lf = 0; lf < 2; ++lf)
      store_bf4(rowp + lf * 16, acc[ef][lf], bias);
  }

  // ---- Q GEMM -> qz (bf16, upper 32KiB of out-region rows; sigmoid in K5)
  #pragma unroll
  for (int ef = 0; ef < 4; ++ef)
    #pragma unroll
    for (int lf = 0; lf < 2; ++lf)
      acc[ef][lf] = (f32x4){0.f, 0.f, 0.f, 0.f};
  gemm64x32(qwb + e0 * 256, xsl, lane, acc);
  #pragma unroll
  for (int ef = 0; ef < 4; ++ef) {
    int e = e0 + ef * 16 + r;
    float bias = q_b[e];
    short* rowp = qzS + (((size_t)((b << 8) | e) << 15) + 16384) + lbase;
    #pragma unroll
    for (int lf = 0; lf < 2; ++lf)
      store_bf4(rowp + lf * 16, acc[ef][lf], bias);
  }

  // ---- gates: 4x256 GEMM on waves with we==0 (wl = 0,1 -> two 32-l halves)
  if (we == 0) {
    f32x4 gacc[2];
    gacc[0] = (f32x4){0.f, 0.f, 0.f, 0.f};
    gacc[1] = (f32x4){0.f, 0.f, 0.f, 0.f};
    #pragma unroll
    for (int k0 = 0; k0 < 256; k0 += 32) {
      bf16x8 wfr = *(const bf16x8*)(gwb + r * 256 + k0 + 8 * h);
      #pragma unroll
      for (int lf = 0; lf < 2; ++lf) {
        bf16x8 xfr = *(const bf16x8*)&xsl[lf * 16 + r][k0 + 8 * h];
        gacc[lf] = __builtin_amdgcn_mfma_f32_16x16x32_bf16(xfr, wfr, gacc[lf], 0, 0, 0);
      }
    }
    if (r < 4) {  // col = gate row g = r; rows l = lbase + lf*16 + i
      float gb = g_b[r];
      float* gp = gates + (((size_t)((b << 2) | r)) << 14) + lbase;
      #pragma unroll
      for (int lf = 0; lf < 2; ++lf) {
        float4 o = {gacc[lf][0] + gb, gacc[lf][1] + gb,
                    gacc[lf][2] + gb, gacc[lf][3] + gb};
        *(float4*)(gp + lf * 16) = o;
      }
    }
  }
}

// ---------------- K2: fused 3-level depthwise conv + gelu chain,
//                      acc3 (bf16) -> lower half of mask rows; rowsum atomics ----
__global__ __launch_bounds__(256) void k2_conv(
    const short* __restrict__ focus0, const float* __restrict__ gates,
    const float* __restrict__ f0_w, const float* __restrict__ f1_w,
    const float* __restrict__ f2_w, short* __restrict__ acc3S,
    float* __restrict__ rowsum) {
  int bx = blockIdx.x;
  int b = bx >> 12, c = (bx >> 4) & 255, lt = bx & 15;
  int l0 = lt << 10;
  __shared__ float s0[1036], s1[1034], s2[1030];
  __shared__ float rs[4];
  int t = threadIdx.x;
  const short* fp = focus0 + ((size_t)((b << 8) | c) << 14);
  for (int i = t; i < 1036; i += 256) {
    int gl = l0 - 6 + i;
    s0[i] = (gl >= 0 && gl < LLEN) ? bf2f(fp[gl]) : 0.f;
  }
  float w0[3], w1[5], w2[7];
  #pragma unroll
  for (int j = 0; j < 3; ++j) w0[j] = f0_w[c * 3 + j];
  #pragma unroll
  for (int j = 0; j < 5; ++j) w1[j] = f1_w[c * 5 + j];
  #pragma unroll
  for (int j = 0; j < 7; ++j) w2[j] = f2_w[c * 7 + j];
  __syncthreads();
  for (int i = t; i < 1034; i += 256) {
    int gl = l0 - 5 + i;
    float z = w0[0] * s0[i] + w0[1] * s0[i + 1] + w0[2] * s0[i + 2];
    s1[i] = (gl >= 0 && gl < LLEN) ? gelu_fast(z) : 0.f;
  }
  __syncthreads();
  for (int i = t; i < 1030; i += 256) {
    int gl = l0 - 3 + i;
    float z = w1[0] * s1[i] + w1[1] * s1[i + 1] + w1[2] * s1[i + 2] +
              w1[3] * s1[i + 3] + w1[4] * s1[i + 4];
    s2[i] = (gl >= 0 && gl < LLEN) ? gelu_fast(z) : 0.f;
  }
  __syncthreads();
  const float* gp = gates + ((size_t)(b << 2) << 14);
  short* op = acc3S + ((size_t)((b << 8) | c) << 15);  // lower 32KiB of mask row
  float lsum = 0.f;
  #pragma unroll
  for (int ii = 0; ii < 2; ++ii) {
    int i = 2 * t + 512 * ii;
    float z0 = w2[0] * s2[i] + w2[1] * s2[i + 1] + w2[2] * s2[i + 2] +
               w2[3] * s2[i + 3] + w2[4] * s2[i + 4] + w2[5] * s2[i + 5] +
               w2[6] * s2[i + 6];
    float z1 = w2[0] * s2[i + 1] + w2[1] * s2[i + 2] + w2[2] * s2[i + 3] +
               w2[3] * s2[i + 4] + w2[4] * s2[i + 5] + w2[5] * s2[i + 6] +
               w2[6] * s2[i + 7];
    float f30 = gelu_fast(z0), f31 = gelu_fast(z1);
    lsum += f30 + f31;
    int l = l0 + i;
    float a0 = s1[i + 5] * gp[l] + s2[i + 3] * gp[LLEN + l] + f30 * gp[2 * LLEN + l];
    float a1 = s1[i + 6] * gp[l + 1] + s2[i + 4] * gp[LLEN + l + 1] +
               f31 * gp[2 * LLEN + l + 1];
    *(unsigned*)&op[l] = bfbits(a0) | (bfbits(a1) << 16);
  }
  float wsv = waveRedSum(lsum);
  if ((t & 63) == 0) rs[t >> 6] = wsv;
  __syncthreads();
  if (t == 0) atomicAdd(&rowsum[(b << 8) | c], rs[0] + rs[1] + rs[2] + rs[3]);
}

// ---------------- K4: m = mix_w @ (acc3 + gelu(mean)*g3) + mix_b -> bf16 ----
// gf computed per-block from rowsum (k3 folded in). 512 thr, 8 waves.
__global__ __launch_bounds__(512) void k4_mix(
    short* maskS, const float* __restrict__ gates, const float* __restrict__ rowsum,
    const short* __restrict__ mwb, const float* __restrict__ mix_b) {
  int b = blockIdx.x >> 8, lt = blockIdx.x & 255;
  int l0 = lt << 6;
  __shared__ short xs[64][PAD];
  __shared__ float gfS[256];
  int t = threadIdx.x;
  if (t < 256) gfS[t] = geluf(rowsum[(b << 8) | t] * (1.0f / 16384.0f));
  __syncthreads();
  {
    int l4 = (t & 15) * 4, cg = t >> 4;
    float4 g3v = *(const float4*)(gates + (((size_t)((b << 2) | 3)) << 14) + l0 + l4);
    const unsigned short* ap =
        (const unsigned short*)maskS + (((size_t)(b << 8)) << 15) + l0 + l4;
    #pragma unroll
    for (int rep = 0; rep < 4; ++rep) {
      int c = rep * 64 + cg * 2;
      uint2 av = *(const uint2*)&ap[(size_t)c << 15];
      uint2 bv = *(const uint2*)&ap[((size_t)c + 1) << 15];
      float gfa = gfS[c], gfb = gfS[c + 1];
      float a0 = bf2f((short)(av.x & 0xFFFF)) + gfa * g3v.x;
      float a1 = bf2f((short)(av.x >> 16)) + gfa * g3v.y;
      float a2 = bf2f((short)(av.y & 0xFFFF)) + gfa * g3v.z;
      float a3 = bf2f((short)(av.y >> 16)) + gfa * g3v.w;
      float b0 = bf2f((short)(bv.x & 0xFFFF)) + gfb * g3v.x;
      float b1 = bf2f((short)(bv.x >> 16)) + gfb * g3v.y;
      float b2 = bf2f((short)(bv.y & 0xFFFF)) + gfb * g3v.z;
      float b3 = bf2f((short)(bv.y >> 16)) + gfb * g3v.w;
      *(unsigned*)&xs[l4 + 0][c] = bfbits(a0) | (bfbits(b0) << 16);
      *(unsigned*)&xs[l4 + 1][c] = bfbits(a1) | (bfbits(b1) << 16);
      *(unsigned*)&xs[l4 + 2][c] = bfbits(a2) | (bfbits(b2) << 16);
      *(unsigned*)&xs[l4 + 3][c] = bfbits(a3) | (bfbits(b3) << 16);
    }
  }
  __syncthreads();
  int lane = t & 63, wave = t >> 6;
  int we = wave & 3, wl = wave >> 2;
  int r = lane & 15, h = lane >> 4;
  int e0 = we << 6;
  const short (*xsl)[PAD] = (const short (*)[PAD])&xs[wl << 5];
  int lbase = l0 + (wl << 5) + 4 * h;
  f32x4 acc[4][2];
  #pragma unroll
  for (int ef = 0; ef < 4; ++ef)
    #pragma unroll
    for (int lf = 0; lf < 2; ++lf)
      acc[ef][lf] = (f32x4){0.f, 0.f, 0.f, 0.f};
  gemm64x32(mwb + e0 * 256, xsl, lane, acc);
  #pragma unroll
  for (int ef = 0; ef < 4; ++ef) {
    int o = e0 + ef * 16 + r;
    float bias = mix_b[o];
    short* rowp = maskS + (((size_t)((b << 8) | o) << 15) + 16384) + lbase;
    #pragma unroll
    for (int lf = 0; lf < 2; ++lf)
      store_bf4(rowp + lf * 16, acc[ef][lf], bias);
  }
}

// ---------------- K5: softmax over L from bf16 m; out = sigmoid(qz)*mask ----
__global__ __launch_bounds__(512) void k5_softmax(
    const short* __restrict__ maskS, const short* __restrict__ outS,
    float* __restrict__ maskF, float* __restrict__ outF) {
  int row = blockIdx.x;  // b*256 + o
  int t = threadIdx.x;   // 512 threads, 8 waves
  const short* mrow = maskS + ((size_t)row << 15) + 16384;
  const short* qrow = outS + ((size_t)row << 15) + 16384;
  float* mw = maskF + ((size_t)row << 14);
  float* ow = outF + ((size_t)row << 14);
  int lane = t & 63, wave = t >> 6;
  bf16x8 qv[4];
  float f[32];
  float lm = -3.0e38f;
  #pragma unroll
  for (int i = 0; i < 4; ++i) {
    bf16x8 mv = *(const bf16x8*)&mrow[i * 4096 + t * 8];
    qv[i] = *(const bf16x8*)&qrow[i * 4096 + t * 8];
    #pragma unroll
    for (int j = 0; j < 8; ++j) {
      float vf = bf2f(mv[j]);
      f[i * 8 + j] = vf;
      lm = fmaxf(lm, vf);
    }
  }
  __shared__ float redm[8], reds[8];
  {
    #pragma unroll
    for (int o = 32; o > 0; o >>= 1) lm = fmaxf(lm, __shfl_xor(lm, o, 64));
  }
  if (lane == 0) redm[wave] = lm;
  __syncthreads();  // also drains all global loads (vmcnt) before writes below
  float M = redm[0];
  #pragma unroll
  for (int w = 1; w < 8; ++w) M = fmaxf(M, redm[w]);
  float ls = 0.f;
  #pragma unroll
  for (int k = 0; k < 32; ++k) {
    f[k] = __expf(f[k] - M);
    ls += f[k];
  }
  float wsum = waveRedSum(ls);
  if (lane == 0) reds[wave] = wsum;
  __syncthreads();
  float S = reds[0];
  #pragma unroll
  for (int w = 1; w < 8; ++w) S += reds[w];
  float inv = 1.0f / S;
  #pragma unroll
  for (int i = 0; i < 4; ++i) {
    float mk[8], oo[8];
    #pragma unroll
    for (int j = 0; j < 8; ++j) {
      mk[j] = f[i * 8 + j] * inv;
      float sig = 1.0f / (1.0f + __expf(-bf2f(qv[i][j])));
      oo[j] = sig * mk[j];
    }
    float* mp = &mw[i * 4096 + t * 8];
    float* op = &ow[i * 4096 + t * 8];
    *(float4*)mp = (float4){mk[0], mk[1], mk[2], mk[3]};
    *(float4*)(mp + 4) = (float4){mk[4], mk[5], mk[6], mk[7]};
    *(float4*)op = (float4){oo[0], oo[1], oo[2], oo[3]};
    *(float4*)(op + 4) = (float4){oo[4], oo[5], oo[6], oo[7]};
  }
}

extern "C" void kernel_launch(void* const* d_in, const int* in_sizes, int n_in,
                              void* d_out, int out_size, void* d_ws, size_t ws_size,
                              hipStream_t stream) {
  const float* x     = (const float*)d_in[0];
  const float* q_w   = (const float*)d_in[1];
  const float* q_b   = (const float*)d_in[2];
  const float* v_w   = (const float*)d_in[3];
  const float* v_b   = (const float*)d_in[4];
  const float* g_w   = (const float*)d_in[5];
  const float* g_b   = (const float*)d_in[6];
  const float* f0_w  = (const float*)d_in[7];
  const float* f1_w  = (const float*)d_in[8];
  const float* f2_w  = (const float*)d_in[9];
  const float* mix_w = (const float*)d_in[10];
  const float* mix_b = (const float*)d_in[11];

  float* outbuf  = (float*)d_out;                       // out [8,256,16384] f32
  float* maskbuf = outbuf + (size_t)8 * 256 * 16384;    // mask [8,256,16384] f32
  short* outS  = (short*)outbuf;   // per-row: [32KiB out f32][32KiB qz bf16]
  short* maskS = (short*)maskbuf;  // per-row: [32KiB acc3 bf16][32KiB m bf16]

  char* ws = (char*)d_ws;
  short* vwb    = (short*)(ws + 0);        // 131072 B
  short* qwb    = (short*)(ws + 131072);   // 131072 B
  short* mwb    = (short*)(ws + 262144);   // 131072 B
  short* gwb    = (short*)(ws + 393216);   // 8192 B (16x256 bf16, rows>=4 zero)
  float* rowsum = (float*)(ws + 401408);   // 8192 B
  float* gates  = (float*)(ws + 417792);   // 2097152 B
  short* focus0 = (short*)(ws + 2514944);  // 67108864 B

  k0_convert<<<dim3(256), dim3(256), 0, stream>>>(q_w, v_w, g_w, mix_w,
                                                  qwb, vwb, gwb, mwb, rowsum);
  k1_qvg<<<dim3(2048), dim3(512), 0, stream>>>(x, vwb, qwb, gwb, v_b, q_b, g_b,
                                               focus0, outS, gates);
  k2_conv<<<dim3(32768), dim3(256), 0, stream>>>(focus0, gates, f0_w, f1_w, f2_w,
                                                 maskS, rowsum);
  k4_mix<<<dim3(2048), dim3(512), 0, stream>>>(maskS, gates, rowsum, mwb, mix_b);
  k5_softmax<<<dim3(2048), dim3(512), 0, stream>>>(maskS, outS, maskbuf, outbuf);
}

// Round 6
// 365.762 us; speedup vs baseline: 1.2449x; 1.2449x over previous
//
#include <hip/hip_runtime.h>

#define LLEN 16384
#define PAD 258  // 516B row stride = 129 dwords; 129%32==1 -> 2-way (free) LDS aliasing

typedef short bf16x8 __attribute__((ext_vector_type(8)));
typedef float f32x4 __attribute__((ext_vector_type(4)));

__device__ __forceinline__ unsigned bfbits(float f) {
  union { float f; unsigned u; } v; v.f = f;
  return (v.u + 0x7FFFu + ((v.u >> 16) & 1u)) >> 16;
}
__device__ __forceinline__ short f2bf(float f) { return (short)bfbits(f); }
__device__ __forceinline__ float bf2f(short s) {
  union { unsigned u; float f; } v;
  v.u = ((unsigned)(unsigned short)s) << 16;
  return v.f;
}
__device__ __forceinline__ float geluf(float x) {  // exact (gf path only)
  return 0.5f * x * (1.0f + erff(x * 0.70710678118654752f));
}
// Fast GELU for the conv chain: activations are ~0.01-0.1 scale there, where
// x*sigmoid(1.702x) differs from exact erf-GELU by <1e-4 abs -> ~1e-10 on
// mask, far below the bf16 path's existing 5e-7. (verified R4/R5: absmax
// unchanged at 4.77e-7)
__device__ __forceinline__ float gelu_fast(float x) {
  return x / (1.0f + __expf(-1.702f * x));
}
__device__ __forceinline__ float waveRedSum(float v) {
  #pragma unroll
  for (int o = 32; o > 0; o >>= 1) v += __shfl_xor(v, o, 64);
  return v;
}

// ---------------- K0: weights -> bf16, zero rowsum ----------------
__global__ __launch_bounds__(256) void k0_convert(
    const float* __restrict__ qw, const float* __restrict__ vw,
    const float* __restrict__ gw, const float* __restrict__ mw,
    short* __restrict__ qwb, short* __restrict__ vwb,
    short* __restrict__ gwb, short* __restrict__ mwb,
    float* __restrict__ rowsum) {
  int idx = blockIdx.x * 256 + threadIdx.x;  // 65536 threads
  qwb[idx] = f2bf(qw[idx]);
  vwb[idx] = f2bf(vw[idx]);
  mwb[idx] = f2bf(mw[idx]);
  if (idx < 4096) {
    int r = idx >> 8, c = idx & 255;
    gwb[idx] = (r < 4) ? f2bf(gw[r * 256 + c]) : (short)0;
  }
  if (idx < 2048) rowsum[idx] = 0.f;
}

// 64x64-per-wave GEMM over K=256 from LDS tile xs[l][c] (bf16, padded PAD).
// SWAPPED operands: A = x fragment (M = l), B = weight fragment (N = e).
// acc[ef][lf][i] <-> e = ef*16 + (lane&15), l = lf*16 + 4*(lane>>4) + i
// (i = 0..3 are CONSECUTIVE l -> enables packed 8B bf16 stores.)
__device__ __forceinline__ void gemm64(const short* __restrict__ wmat,
                                       const short xs[64][PAD], int lane,
                                       f32x4 acc[4][4]) {
  int r = lane & 15, h = lane >> 4;
  #pragma unroll
  for (int k0 = 0; k0 < 256; k0 += 32) {
    bf16x8 xfr[4];
    #pragma unroll
    for (int lf = 0; lf < 4; ++lf)
      xfr[lf] = *(const bf16x8*)&xs[lf * 16 + r][k0 + 8 * h];
    #pragma unroll
    for (int ef = 0; ef < 4; ++ef) {
      bf16x8 wfr = *(const bf16x8*)(wmat + (ef * 16 + r) * 256 + k0 + 8 * h);
      #pragma unroll
      for (int lf = 0; lf < 4; ++lf)
        acc[ef][lf] = __builtin_amdgcn_mfma_f32_16x16x32_bf16(xfr[lf], wfr,
                                                              acc[ef][lf], 0, 0, 0);
    }
  }
}

// Packed epilogue: 4 consecutive-l f32 + bias -> 2 dwords of bf16 (8B store)
__device__ __forceinline__ void store_bf4(short* p, f32x4 a, float bias) {
  uint2 pk;
  pk.x = bfbits(a[0] + bias) | (bfbits(a[1] + bias) << 16);
  pk.y = bfbits(a[2] + bias) | (bfbits(a[3] + bias) << 16);
  *(uint2*)p = pk;
}

// ---------------- K1: focus0 = v_w@x+v_b (bf16), qz = q_w@x+q_b (bf16),
//                      gates = g_w@x+g_b.  256 thr, 4 waves of 64e x 64l
//                      (R3 geometry: proven fastest shape) ----------------
__global__ __launch_bounds__(256) void k1_qvg(
    const float* __restrict__ x, const short* __restrict__ vwb,
    const short* __restrict__ qwb, const short* __restrict__ gwb,
    const float* __restrict__ v_b, const float* __restrict__ q_b,
    const float* __restrict__ g_b, short* __restrict__ focus0,
    short* __restrict__ qzS, float* __restrict__ gates) {
  int b = blockIdx.x >> 8, lt = blockIdx.x & 255;
  int l0 = lt << 6;
  __shared__ short xs[64][PAD];
  int t = threadIdx.x;
  {
    int l2 = (t & 31) * 2, cg = t >> 5;  // 32 l-pairs x 8 c-groups
    const float* xb = x + ((size_t)b << 22) + l0 + l2;
    #pragma unroll 4
    for (int rep = 0; rep < 16; ++rep) {
      int c = rep * 16 + cg * 2;
      float2 a = *(const float2*)&xb[(size_t)c << 14];
      float2 bb = *(const float2*)&xb[((size_t)c + 1) << 14];
      *(unsigned*)&xs[l2][c] = bfbits(a.x) | (bfbits(bb.x) << 16);
      *(unsigned*)&xs[l2 + 1][c] = bfbits(a.y) | (bfbits(bb.y) << 16);
    }
  }
  __syncthreads();
  int lane = t & 63, wave = t >> 6;
  int r = lane & 15, h = lane >> 4;
  int e0 = wave << 6;
  f32x4 acc[4][4];

  // ---- V GEMM -> focus0 (bf16)
  #pragma unroll
  for (int ef = 0; ef < 4; ++ef)
    #pragma unroll
    for (int lf = 0; lf < 4; ++lf)
      acc[ef][lf] = (f32x4){0.f, 0.f, 0.f, 0.f};
  gemm64(vwb + e0 * 256, xs, lane, acc);
  #pragma unroll
  for (int ef = 0; ef < 4; ++ef) {
    int e = e0 + ef * 16 + r;
    float bias = v_b[e];
    short* rowp = focus0 + ((size_t)((b << 8) | e) << 14) + l0 + 4 * h;
    #pragma unroll
    for (int lf = 0; lf < 4; ++lf)
      store_bf4(rowp + lf * 16, acc[ef][lf], bias);
  }

  // ---- Q GEMM -> qz (bf16, upper 32KiB of out-region rows; sigmoid in K5)
  #pragma unroll
  for (int ef = 0; ef < 4; ++ef)
    #pragma unroll
    for (int lf = 0; lf < 4; ++lf)
      acc[ef][lf] = (f32x4){0.f, 0.f, 0.f, 0.f};
  gemm64(qwb + e0 * 256, xs, lane, acc);
  #pragma unroll
  for (int ef = 0; ef < 4; ++ef) {
    int e = e0 + ef * 16 + r;
    float bias = q_b[e];
    short* rowp = qzS + (((size_t)((b << 8) | e) << 15) + 16384) + l0 + 4 * h;
    #pragma unroll
    for (int lf = 0; lf < 4; ++lf)
      store_bf4(rowp + lf * 16, acc[ef][lf], bias);
  }

  // ---- gates: 4x256 GEMM on wave 0 only (16-row padded weight tile)
  if (wave == 0) {
    f32x4 gacc[4];
    #pragma unroll
    for (int lf = 0; lf < 4; ++lf) gacc[lf] = (f32x4){0.f, 0.f, 0.f, 0.f};
    #pragma unroll
    for (int k0 = 0; k0 < 256; k0 += 32) {
      bf16x8 wfr = *(const bf16x8*)(gwb + r * 256 + k0 + 8 * h);
      #pragma unroll
      for (int lf = 0; lf < 4; ++lf) {
        bf16x8 xfr = *(const bf16x8*)&xs[lf * 16 + r][k0 + 8 * h];
        gacc[lf] = __builtin_amdgcn_mfma_f32_16x16x32_bf16(xfr, wfr, gacc[lf], 0, 0, 0);
      }
    }
    if (r < 4) {  // col = gate row g = r; rows = l = lf*16 + 4h + i
      float gb = g_b[r];
      float* gp = gates + (((size_t)((b << 2) | r)) << 14) + l0 + 4 * h;
      #pragma unroll
      for (int lf = 0; lf < 4; ++lf) {
        float4 o = {gacc[lf][0] + gb, gacc[lf][1] + gb,
                    gacc[lf][2] + gb, gacc[lf][3] + gb};
        *(float4*)(gp + lf * 16) = o;
      }
    }
  }
}

// ---------------- K2: fused 3-level depthwise conv + gelu chain,
//                      acc3 (bf16) -> lower half of mask rows; rowsum atomics ----
__global__ __launch_bounds__(256) void k2_conv(
    const short* __restrict__ focus0, const float* __restrict__ gates,
    const float* __restrict__ f0_w, const float* __restrict__ f1_w,
    const float* __restrict__ f2_w, short* __restrict__ acc3S,
    float* __restrict__ rowsum) {
  int bx = blockIdx.x;
  int b = bx >> 12, c = (bx >> 4) & 255, lt = bx & 15;
  int l0 = lt << 10;
  __shared__ float s0[1036], s1[1034], s2[1030];
  __shared__ float rs[4];
  int t = threadIdx.x;
  const short* fp = focus0 + ((size_t)((b << 8) | c) << 14);
  if (lt > 0 && lt < 15) {
    // interior: [l0-6, l0+1030) fully in range; dword loads (2 bf16 each)
    const unsigned* fp2 = (const unsigned*)(fp + l0 - 6);
    for (int i2 = t; i2 < 518; i2 += 256) {
      unsigned u = fp2[i2];
      s0[2 * i2] = bf2f((short)(u & 0xFFFF));
      s0[2 * i2 + 1] = bf2f((short)(u >> 16));
    }
  } else {
    for (int i = t; i < 1036; i += 256) {
      int gl = l0 - 6 + i;
      s0[i] = (gl >= 0 && gl < LLEN) ? bf2f(fp[gl]) : 0.f;
    }
  }
  float w0[3], w1[5], w2[7];
  #pragma unroll
  for (int j = 0; j < 3; ++j) w0[j] = f0_w[c * 3 + j];
  #pragma unroll
  for (int j = 0; j < 5; ++j) w1[j] = f1_w[c * 5 + j];
  #pragma unroll
  for (int j = 0; j < 7; ++j) w2[j] = f2_w[c * 7 + j];
  __syncthreads();
  for (int i = t; i < 1034; i += 256) {
    int gl = l0 - 5 + i;
    float z = w0[0] * s0[i] + w0[1] * s0[i + 1] + w0[2] * s0[i + 2];
    s1[i] = (gl >= 0 && gl < LLEN) ? gelu_fast(z) : 0.f;
  }
  __syncthreads();
  for (int i = t; i < 1030; i += 256) {
    int gl = l0 - 3 + i;
    float z = w1[0] * s1[i] + w1[1] * s1[i + 1] + w1[2] * s1[i + 2] +
              w1[3] * s1[i + 3] + w1[4] * s1[i + 4];
    s2[i] = (gl >= 0 && gl < LLEN) ? gelu_fast(z) : 0.f;
  }
  __syncthreads();
  const float* gp = gates + ((size_t)(b << 2) << 14);
  short* op = acc3S + ((size_t)((b << 8) | c) << 15);  // lower 32KiB of mask row
  float lsum = 0.f;
  #pragma unroll
  for (int ii = 0; ii < 2; ++ii) {
    int i = 2 * t + 512 * ii;
    float z0 = w2[0] * s2[i] + w2[1] * s2[i + 1] + w2[2] * s2[i + 2] +
               w2[3] * s2[i + 3] + w2[4] * s2[i + 4] + w2[5] * s2[i + 5] +
               w2[6] * s2[i + 6];
    float z1 = w2[0] * s2[i + 1] + w2[1] * s2[i + 2] + w2[2] * s2[i + 3] +
               w2[3] * s2[i + 4] + w2[4] * s2[i + 5] + w2[5] * s2[i + 6] +
               w2[6] * s2[i + 7];
    float f30 = gelu_fast(z0), f31 = gelu_fast(z1);
    lsum += f30 + f31;
    int l = l0 + i;
    float a0 = s1[i + 5] * gp[l] + s2[i + 3] * gp[LLEN + l] + f30 * gp[2 * LLEN + l];
    float a1 = s1[i + 6] * gp[l + 1] + s2[i + 4] * gp[LLEN + l + 1] +
               f31 * gp[2 * LLEN + l + 1];
    *(unsigned*)&op[l] = bfbits(a0) | (bfbits(a1) << 16);
  }
  float wsv = waveRedSum(lsum);
  if ((t & 63) == 0) rs[t >> 6] = wsv;
  __syncthreads();
  if (t == 0) atomicAdd(&rowsum[(b << 8) | c], rs[0] + rs[1] + rs[2] + rs[3]);
}

// ---------------- K4: m = mix_w @ (acc3 + gelu(mean)*g3) + mix_b -> bf16 ----
// gf computed per-block from rowsum (k3 folded in). 256 thr, 4 waves (R3 shape).
__global__ __launch_bounds__(256) void k4_mix(
    short* maskS, const float* __restrict__ gates, const float* __restrict__ rowsum,
    const short* __restrict__ mwb, const float* __restrict__ mix_b) {
  int b = blockIdx.x >> 8, lt = blockIdx.x & 255;
  int l0 = lt << 6;
  __shared__ short xs[64][PAD];
  __shared__ float gfS[256];
  int t = threadIdx.x;
  gfS[t] = geluf(rowsum[(b << 8) | t] * (1.0f / 16384.0f));
  __syncthreads();
  {
    int l2 = (t & 31) * 2, cg = t >> 5;
    float2 g3v = *(const float2*)(gates + (((size_t)((b << 2) | 3)) << 14) + l0 + l2);
    const unsigned short* ap =
        (const unsigned short*)maskS + (((size_t)(b << 8)) << 15) + l0 + l2;
    #pragma unroll 4
    for (int rep = 0; rep < 16; ++rep) {
      int c = rep * 16 + cg * 2;
      unsigned av = *(const unsigned*)&ap[(size_t)c << 15];
      unsigned bv = *(const unsigned*)&ap[((size_t)c + 1) << 15];
      float gfa = gfS[c], gfb = gfS[c + 1];
      float a0 = bf2f((short)(av & 0xFFFF)) + gfa * g3v.x;
      float a1 = bf2f((short)(av >> 16)) + gfa * g3v.y;
      float b0 = bf2f((short)(bv & 0xFFFF)) + gfb * g3v.x;
      float b1 = bf2f((short)(bv >> 16)) + gfb * g3v.y;
      *(unsigned*)&xs[l2][c] = bfbits(a0) | (bfbits(b0) << 16);
      *(unsigned*)&xs[l2 + 1][c] = bfbits(a1) | (bfbits(b1) << 16);
    }
  }
  __syncthreads();
  int lane = t & 63, wave = t >> 6;
  int r = lane & 15, h = lane >> 4;
  int e0 = wave << 6;
  f32x4 acc[4][4];
  #pragma unroll
  for (int ef = 0; ef < 4; ++ef)
    #pragma unroll
    for (int lf = 0; lf < 4; ++lf)
      acc[ef][lf] = (f32x4){0.f, 0.f, 0.f, 0.f};
  gemm64(mwb + e0 * 256, xs, lane, acc);
  #pragma unroll
  for (int ef = 0; ef < 4; ++ef) {
    int o = e0 + ef * 16 + r;
    float bias = mix_b[o];
    short* rowp = maskS + (((size_t)((b << 8) | o) << 15) + 16384) + l0 + 4 * h;
    #pragma unroll
    for (int lf = 0; lf < 4; ++lf)
      store_bf4(rowp + lf * 16, acc[ef][lf], bias);
  }
}

// ---------------- K5: softmax over L from bf16 m; out = sigmoid(qz)*mask ----
__global__ __launch_bounds__(512) void k5_softmax(
    const short* __restrict__ maskS, const short* __restrict__ outS,
    float* __restrict__ maskF, float* __restrict__ outF) {
  int row = blockIdx.x;  // b*256 + o
  int t = threadIdx.x;   // 512 threads, 8 waves
  const short* mrow = maskS + ((size_t)row << 15) + 16384;
  const short* qrow = outS + ((size_t)row << 15) + 16384;
  float* mw = maskF + ((size_t)row << 14);
  float* ow = outF + ((size_t)row << 14);
  int lane = t & 63, wave = t >> 6;
  bf16x8 qv[4];
  float f[32];
  float lm = -3.0e38f;
  #pragma unroll
  for (int i = 0; i < 4; ++i) {
    bf16x8 mv = *(const bf16x8*)&mrow[i * 4096 + t * 8];
    qv[i] = *(const bf16x8*)&qrow[i * 4096 + t * 8];
    #pragma unroll
    for (int j = 0; j < 8; ++j) {
      float vf = bf2f(mv[j]);
      f[i * 8 + j] = vf;
      lm = fmaxf(lm, vf);
    }
  }
  __shared__ float redm[8], reds[8];
  {
    #pragma unroll
    for (int o = 32; o > 0; o >>= 1) lm = fmaxf(lm, __shfl_xor(lm, o, 64));
  }
  if (lane == 0) redm[wave] = lm;
  __syncthreads();  // also drains all global loads (vmcnt) before writes below
  float M = redm[0];
  #pragma unroll
  for (int w = 1; w < 8; ++w) M = fmaxf(M, redm[w]);
  float ls = 0.f;
  #pragma unroll
  for (int k = 0; k < 32; ++k) {
    f[k] = __expf(f[k] - M);
    ls += f[k];
  }
  float wsum = waveRedSum(ls);
  if (lane == 0) reds[wave] = wsum;
  __syncthreads();
  float S = reds[0];
  #pragma unroll
  for (int w = 1; w < 8; ++w) S += reds[w];
  float inv = 1.0f / S;
  #pragma unroll
  for (int i = 0; i < 4; ++i) {
    float mk[8], oo[8];
    #pragma unroll
    for (int j = 0; j < 8; ++j) {
      mk[j] = f[i * 8 + j] * inv;
      float sig = 1.0f / (1.0f + __expf(-bf2f(qv[i][j])));
      oo[j] = sig * mk[j];
    }
    float* mp = &mw[i * 4096 + t * 8];
    float* op = &ow[i * 4096 + t * 8];
    *(float4*)mp = (float4){mk[0], mk[1], mk[2], mk[3]};
    *(float4*)(mp + 4) = (float4){mk[4], mk[5], mk[6], mk[7]};
    *(float4*)op = (float4){oo[0], oo[1], oo[2], oo[3]};
    *(float4*)(op + 4) = (float4){oo[4], oo[5], oo[6], oo[7]};
  }
}

extern "C" void kernel_launch(void* const* d_in, const int* in_sizes, int n_in,
                              void* d_out, int out_size, void* d_ws, size_t ws_size,
                              hipStream_t stream) {
  const float* x     = (const float*)d_in[0];
  const float* q_w   = (const float*)d_in[1];
  const float* q_b   = (const float*)d_in[2];
  const float* v_w   = (const float*)d_in[3];
  const float* v_b   = (const float*)d_in[4];
  const float* g_w   = (const float*)d_in[5];
  const float* g_b   = (const float*)d_in[6];
  const float* f0_w  = (const float*)d_in[7];
  const float* f1_w  = (const float*)d_in[8];
  const float* f2_w  = (const float*)d_in[9];
  const float* mix_w = (const float*)d_in[10];
  const float* mix_b = (const float*)d_in[11];

  float* outbuf  = (float*)d_out;                       // out [8,256,16384] f32
  float* maskbuf = outbuf + (size_t)8 * 256 * 16384;    // mask [8,256,16384] f32
  short* outS  = (short*)outbuf;   // per-row: [32KiB out f32][32KiB qz bf16]
  short* maskS = (short*)maskbuf;  // per-row: [32KiB acc3 bf16][32KiB m bf16]

  char* ws = (char*)d_ws;
  short* vwb    = (short*)(ws + 0);        // 131072 B
  short* qwb    = (short*)(ws + 131072);   // 131072 B
  short* mwb    = (short*)(ws + 262144);   // 131072 B
  short* gwb    = (short*)(ws + 393216);   // 8192 B (16x256 bf16, rows>=4 zero)
  float* rowsum = (float*)(ws + 401408);   // 8192 B
  float* gates  = (float*)(ws + 417792);   // 2097152 B
  short* focus0 = (short*)(ws + 2514944);  // 67108864 B

  k0_convert<<<dim3(256), dim3(256), 0, stream>>>(q_w, v_w, g_w, mix_w,
                                                  qwb, vwb, gwb, mwb, rowsum);
  k1_qvg<<<dim3(2048), dim3(256), 0, stream>>>(x, vwb, qwb, gwb, v_b, q_b, g_b,
                                               focus0, outS, gates);
  k2_conv<<<dim3(32768), dim3(256), 0, stream>>>(focus0, gates, f0_w, f1_w, f2_w,
                                                 maskS, rowsum);
  k4_mix<<<dim3(2048), dim3(256), 0, stream>>>(maskS, gates, rowsum, mwb, mix_b);
  k5_softmax<<<dim3(2048), dim3(512), 0, stream>>>(maskS, outS, maskbuf, outbuf);
}